// Round 1
// baseline (277.600 us; speedup 1.0000x reference)
//
#include <hip/hip_runtime.h>

#define BB 16
#define T_K 2048
#define SENT_T 64
#define NN 512

// fast tanh via hardware exp: exact at saturation (exp overflow -> 1, underflow -> -1)
__device__ __forceinline__ float fast_tanh(float x) {
    return 1.f - 2.f / (1.f + __expf(2.f * x));
}

// dec[b,n] = sum_k s[b,k] * W[n,k] + bias[n]
__global__ __launch_bounds__(256) void dec_kernel(
    const float* __restrict__ s,    // [B,N]
    const float* __restrict__ W,    // [N,N] row-major
    const float* __restrict__ bias, // [N]
    float* __restrict__ out)        // [B,N]
{
    int b = blockIdx.x;
    __shared__ float sv[NN];
    for (int i = threadIdx.x; i < NN; i += blockDim.x) sv[i] = s[b * NN + i];
    __syncthreads();
    for (int n = threadIdx.x; n < NN; n += blockDim.x) {
        const float4* Wr = reinterpret_cast<const float4*>(W + (size_t)n * NN);
        float acc = 0.f;
#pragma unroll 8
        for (int k = 0; k < NN / 4; ++k) {
            float4 w4 = Wr[k];
            acc = fmaf(w4.x, sv[4 * k + 0], acc);
            acc = fmaf(w4.y, sv[4 * k + 1], acc);
            acc = fmaf(w4.z, sv[4 * k + 2], acc);
            acc = fmaf(w4.w, sv[4 * k + 3], acc);
        }
        out[b * NN + n] = acc + bias[n];
    }
}

// one wave per row: scores[row] = sum_n v[n]*tanh(feat[row,n] + dec[b,n] + cov[row]*wc[n])
template <bool HASCOV>
__global__ __launch_bounds__(256) void scores_kernel(
    const float* __restrict__ feat,  // [B*T, N]
    const float* __restrict__ dec,   // [B, N]
    const float* __restrict__ v,     // [N]
    const float* __restrict__ wc,    // [N] (HASCOV)
    const float* __restrict__ cov,   // [B*T] (HASCOV)
    float* __restrict__ scores,      // [B*T]
    int T)
{
    int wave = (blockIdx.x * blockDim.x + threadIdx.x) >> 6;
    int lane = threadIdx.x & 63;
    int b = wave / T;
    float c = HASCOV ? cov[wave] : 0.f;
    const float4* f4 = reinterpret_cast<const float4*>(feat + (size_t)wave * NN);
    const float4* d4 = reinterpret_cast<const float4*>(dec + (size_t)b * NN);
    const float4* v4 = reinterpret_cast<const float4*>(v);
    const float4* w4 = reinterpret_cast<const float4*>(wc);
    float acc = 0.f;
#pragma unroll
    for (int i = 0; i < 2; ++i) {
        int idx = lane + 64 * i;       // float4 index within row [0,128)
        float4 f = f4[idx];
        float4 d = d4[idx];
        float4 vv = v4[idx];
        float ex = 0.f, ey = 0.f, ez = 0.f, ew = 0.f;
        if (HASCOV) {
            float4 w = w4[idx];
            ex = c * w.x; ey = c * w.y; ez = c * w.z; ew = c * w.w;
        }
        acc += vv.x * fast_tanh(f.x + d.x + ex);
        acc += vv.y * fast_tanh(f.y + d.y + ey);
        acc += vv.z * fast_tanh(f.z + d.z + ez);
        acc += vv.w * fast_tanh(f.w + d.w + ew);
    }
    for (int off = 32; off; off >>= 1) acc += __shfl_down(acc, off, 64);
    if (lane == 0) scores[wave] = acc;
}

// per-b sentence softmax (64 vals, one wave) + sent_c_t (256 threads over N)
__global__ __launch_bounds__(256) void sent_softmax_ct(
    float* __restrict__ attn,        // [B,64]  in: scores, out: attn
    const float* __restrict__ mask,  // [B,64]
    const float* __restrict__ enc,   // [B,64,N]
    float* __restrict__ ct)          // [B,N]
{
    int b = blockIdx.x, tid = threadIdx.x;
    __shared__ float a_sh[SENT_T];
    if (tid < SENT_T) {
        float s = attn[b * SENT_T + tid];
        float m = s;
        for (int off = 32; off; off >>= 1) m = fmaxf(m, __shfl_xor(m, off, 64));
        float p = __expf(s - m);
        float sum = p;
        for (int off = 32; off; off >>= 1) sum += __shfl_xor(sum, off, 64);
        float a0 = p / sum * mask[b * SENT_T + tid];
        float s2 = a0;
        for (int off = 32; off; off >>= 1) s2 += __shfl_xor(s2, off, 64);
        float a = a0 / s2;
        attn[b * SENT_T + tid] = a;
        a_sh[tid] = a;
    }
    __syncthreads();
    for (int n = tid; n < NN; n += blockDim.x) {
        float acc = 0.f;
#pragma unroll 8
        for (int t = 0; t < SENT_T; ++t)
            acc = fmaf(a_sh[t], enc[((size_t)b * SENT_T + t) * NN + n], acc);
        ct[b * NN + n] = acc;
    }
}

// per-b word softmax over 2048, in-place (scores were written into the attn slot)
__global__ __launch_bounds__(256) void word_softmax(
    float* __restrict__ attn,        // [B,T_K] in: scores, out: attn
    const float* __restrict__ mask)  // [B,T_K]
{
    int b = blockIdx.x, tid = threadIdx.x;
    __shared__ float sh[4];
    const int base = b * T_K + tid * 8;
    float4 v0 = *reinterpret_cast<const float4*>(attn + base);
    float4 v1 = *reinterpret_cast<const float4*>(attn + base + 4);
    float vv[8] = {v0.x, v0.y, v0.z, v0.w, v1.x, v1.y, v1.z, v1.w};

    float m = vv[0];
#pragma unroll
    for (int i = 1; i < 8; ++i) m = fmaxf(m, vv[i]);
    for (int off = 32; off; off >>= 1) m = fmaxf(m, __shfl_xor(m, off, 64));
    if ((tid & 63) == 0) sh[tid >> 6] = m;
    __syncthreads();
    m = fmaxf(fmaxf(sh[0], sh[1]), fmaxf(sh[2], sh[3]));
    __syncthreads();

    float p[8], s = 0.f;
#pragma unroll
    for (int i = 0; i < 8; ++i) { p[i] = __expf(vv[i] - m); s += p[i]; }
    for (int off = 32; off; off >>= 1) s += __shfl_xor(s, off, 64);
    if ((tid & 63) == 0) sh[tid >> 6] = s;
    __syncthreads();
    s = sh[0] + sh[1] + sh[2] + sh[3];
    __syncthreads();

    float4 m0 = *reinterpret_cast<const float4*>(mask + base);
    float4 m1 = *reinterpret_cast<const float4*>(mask + base + 4);
    float mk[8] = {m0.x, m0.y, m0.z, m0.w, m1.x, m1.y, m1.z, m1.w};
    float a0[8], s2 = 0.f;
#pragma unroll
    for (int i = 0; i < 8; ++i) { a0[i] = p[i] / s * mk[i]; s2 += a0[i]; }
    for (int off = 32; off; off >>= 1) s2 += __shfl_xor(s2, off, 64);
    if ((tid & 63) == 0) sh[tid >> 6] = s2;
    __syncthreads();
    s2 = sh[0] + sh[1] + sh[2] + sh[3];

    float r = 1.f / s2;
    float4 o0 = {a0[0] * r, a0[1] * r, a0[2] * r, a0[3] * r};
    float4 o1 = {a0[4] * r, a0[5] * r, a0[6] * r, a0[7] * r};
    *reinterpret_cast<float4*>(attn + base) = o0;
    *reinterpret_cast<float4*>(attn + base + 4) = o1;
}

// ragged per-sentence renorm + coverage update; one block per b
__global__ __launch_bounds__(256) void seg_kernel(
    const int* __restrict__ pos,      // [B,64] sorted end positions
    const float* __restrict__ attn,   // [B,T_K] final word attn
    const float* __restrict__ senta,  // [B,64] sent attn
    const float* __restrict__ cov,    // [B,T_K]
    float* __restrict__ cov_out)      // [B,T_K]
{
    int b = blockIdx.x, tid = threadIdx.x;
    __shared__ int ends[SENT_T];
    __shared__ float ssum[SENT_T];
    __shared__ float sa[SENT_T];
    if (tid < SENT_T) {
        ends[tid] = pos[b * SENT_T + tid];
        ssum[tid] = 0.f;
        sa[tid] = senta[b * SENT_T + tid];
    }
    __syncthreads();
    int segs[8];
    float av[8];
#pragma unroll
    for (int i = 0; i < 8; ++i) {
        int t = tid + 256 * i;
        int lo = 0, hi = SENT_T;
        while (lo < hi) { int mid = (lo + hi) >> 1; if (ends[mid] <= t) lo = mid + 1; else hi = mid; }
        segs[i] = lo;                          // searchsorted(right) == #ends <= t
        av[i] = attn[b * T_K + t];
        if (lo < SENT_T) atomicAdd(&ssum[lo], av[i]);
    }
    __syncthreads();
#pragma unroll
    for (int i = 0; i < 8; ++i) {
        int t = tid + 256 * i;
        float sw = 0.f;
        if (segs[i] < SENT_T) sw = av[i] / ssum[segs[i]] * sa[segs[i]];
        cov_out[b * T_K + t] = cov[b * T_K + t] + sw;
    }
}

__global__ void zero_kernel(float* __restrict__ p, int n) {
    int i = blockIdx.x * blockDim.x + threadIdx.x;
    if (i < n) p[i] = 0.f;
}

// c_t[b,:] += sum over a 64-token chunk of a[b,t]*enc[b,t,:]
__global__ __launch_bounds__(256) void ct_partial(
    const float* __restrict__ attn,  // [B,T_K]
    const float* __restrict__ enc,   // [B,T_K,N]
    float* __restrict__ ct)          // [B,N] (zeroed)
{
    int b = blockIdx.y, chunk = blockIdx.x, tid = threadIdx.x;
    __shared__ float a_sh[64];
    if (tid < 64) a_sh[tid] = attn[b * T_K + chunk * 64 + tid];
    __syncthreads();
    const float* base = enc + ((size_t)b * T_K + (size_t)chunk * 64) * NN;
    float acc0 = 0.f, acc1 = 0.f;
#pragma unroll 4
    for (int t = 0; t < 64; ++t) {
        float a = a_sh[t];
        acc0 = fmaf(a, base[t * NN + tid], acc0);
        acc1 = fmaf(a, base[t * NN + tid + 256], acc1);
    }
    atomicAdd(&ct[b * NN + tid], acc0);
    atomicAdd(&ct[b * NN + tid + 256], acc1);
}

extern "C" void kernel_launch(void* const* d_in, const int* in_sizes, int n_in,
                              void* d_out, int out_size, void* d_ws, size_t ws_size,
                              hipStream_t stream) {
    const float* s_t_hat          = (const float*)d_in[0];
    const int*   enc_sent_pos     = (const int*)d_in[1];
    const float* encoder_outputs  = (const float*)d_in[2];
    const float* encoder_feature  = (const float*)d_in[3];
    const float* enc_padding_mask = (const float*)d_in[4];
    const float* sent_s_t_hat     = (const float*)d_in[5];
    const float* sent_enc_outputs = (const float*)d_in[6];
    const float* sent_enc_feature = (const float*)d_in[7];
    const float* sent_enc_padding_mask = (const float*)d_in[8];
    const float* coverage         = (const float*)d_in[9];
    const float* W_dec            = (const float*)d_in[10];
    const float* b_dec            = (const float*)d_in[11];
    const float* v_w              = (const float*)d_in[12];
    const float* W_sent_dec       = (const float*)d_in[13];
    const float* b_sent_dec       = (const float*)d_in[14];
    const float* sent_v_w         = (const float*)d_in[15];
    const float* w_c              = (const float*)d_in[16];

    float* out         = (float*)d_out;
    float* c_t         = out;                       // [B,N]     8192
    float* attn_dist   = out + 8192;                // [B,T_K]   32768
    float* coverage_nw = out + 8192 + 32768;        // [B,T_K]   32768
    float* sent_c_t    = out + 8192 + 65536;        // [B,N]     8192
    float* sent_attn   = out + 16384 + 65536;       // [B,64]    1024

    float* ws   = (float*)d_ws;
    float* dec  = ws;            // [B,N]
    float* sdec = ws + BB * NN;  // [B,N]

    // 1) decoder projections
    dec_kernel<<<BB, 256, 0, stream>>>(s_t_hat, W_dec, b_dec, dec);
    dec_kernel<<<BB, 256, 0, stream>>>(sent_s_t_hat, W_sent_dec, b_sent_dec, sdec);

    // 2) scores (written into the attn output slots, softmaxed in-place later)
    scores_kernel<true><<<(BB * T_K) / 4, 256, 0, stream>>>(
        encoder_feature, dec, v_w, w_c, coverage, attn_dist, T_K);
    scores_kernel<false><<<(BB * SENT_T) / 4, 256, 0, stream>>>(
        sent_enc_feature, sdec, sent_v_w, nullptr, nullptr, sent_attn, SENT_T);

    // 3) sentence softmax + sent_c_t
    sent_softmax_ct<<<BB, 256, 0, stream>>>(sent_attn, sent_enc_padding_mask,
                                            sent_enc_outputs, sent_c_t);

    // 4) word softmax in-place
    word_softmax<<<BB, 256, 0, stream>>>(attn_dist, enc_padding_mask);

    // 5) ragged renorm + coverage
    seg_kernel<<<BB, 256, 0, stream>>>(enc_sent_pos, attn_dist, sent_attn,
                                       coverage, coverage_nw);

    // 6) c_t
    zero_kernel<<<(BB * NN + 255) / 256, 256, 0, stream>>>(c_t, BB * NN);
    ct_partial<<<dim3(T_K / 64, BB), 256, 0, stream>>>(attn_dist, encoder_outputs, c_t);
}

// Round 2
// 240.053 us; speedup vs baseline: 1.1564x; 1.1564x over previous
//
#include <hip/hip_runtime.h>

#define BB 16
#define T_K 2048
#define SENT_T 64
#define NN 512
#define WORD_ROWS (BB * T_K)     // 32768
#define SENT_ROWS (BB * SENT_T)  // 1024

// fast tanh via hardware exp: exact at saturation (exp overflow -> 1, underflow -> -1)
__device__ __forceinline__ float fast_tanh(float x) {
    return 1.f - 2.f / (1.f + __expf(2.f * x));
}

// Both decoder projections in one launch. blocks 0..15: word, 16..31: sent.
__global__ __launch_bounds__(256) void dec_fused(
    const float* __restrict__ s_w, const float* __restrict__ W_w, const float* __restrict__ bias_w,
    const float* __restrict__ s_s, const float* __restrict__ W_s, const float* __restrict__ bias_s,
    float* __restrict__ dec, float* __restrict__ sdec)
{
    int blk = blockIdx.x;
    int b = blk & (BB - 1);
    bool sent = blk >= BB;
    const float* s    = sent ? s_s   : s_w;
    const float* W    = sent ? W_s   : W_w;
    const float* bias = sent ? bias_s : bias_w;
    float* out        = sent ? sdec  : dec;

    __shared__ float sv[NN];
    for (int i = threadIdx.x; i < NN; i += 256) sv[i] = s[b * NN + i];
    __syncthreads();
    for (int n = threadIdx.x; n < NN; n += 256) {
        const float4* Wr = reinterpret_cast<const float4*>(W + (size_t)n * NN);
        float acc = 0.f;
#pragma unroll 8
        for (int k = 0; k < NN / 4; ++k) {
            float4 w4 = Wr[k];
            acc = fmaf(w4.x, sv[4 * k + 0], acc);
            acc = fmaf(w4.y, sv[4 * k + 1], acc);
            acc = fmaf(w4.z, sv[4 * k + 2], acc);
            acc = fmaf(w4.w, sv[4 * k + 3], acc);
        }
        out[b * NN + n] = acc + bias[n];
    }
}

// One wave per score row; word rows first, then sent rows. Branch is wave-uniform.
__global__ __launch_bounds__(256) void scores_all(
    const float* __restrict__ feat,  const float* __restrict__ dec,
    const float* __restrict__ v,     const float* __restrict__ wc,
    const float* __restrict__ cov,
    const float* __restrict__ sfeat, const float* __restrict__ sdec,
    const float* __restrict__ sv_,
    float* __restrict__ wscores, float* __restrict__ sscores)
{
    int gw = (blockIdx.x * 256 + threadIdx.x) >> 6;
    int lane = threadIdx.x & 63;
    bool word = gw < WORD_ROWS;
    int row = word ? gw : gw - WORD_ROWS;
    int b = word ? (row >> 11) : (row >> 6);

    const float4* f4 = reinterpret_cast<const float4*>((word ? feat : sfeat) + (size_t)row * NN);
    const float4* d4 = reinterpret_cast<const float4*>((word ? dec : sdec) + (size_t)b * NN);
    const float4* v4 = reinterpret_cast<const float4*>(word ? v : sv_);
    const float4* w4 = reinterpret_cast<const float4*>(wc);
    float c = word ? cov[row] : 0.f;

    float acc = 0.f;
#pragma unroll
    for (int i = 0; i < 2; ++i) {
        int idx = lane + 64 * i;  // float4 index within the 512-float row
        float4 f = f4[idx];
        float4 d = d4[idx];
        float4 vv = v4[idx];
        float ex = 0.f, ey = 0.f, ez = 0.f, ew = 0.f;
        if (word) {
            float4 w = w4[idx];
            ex = c * w.x; ey = c * w.y; ez = c * w.z; ew = c * w.w;
        }
        acc += vv.x * fast_tanh(f.x + d.x + ex);
        acc += vv.y * fast_tanh(f.y + d.y + ey);
        acc += vv.z * fast_tanh(f.z + d.z + ez);
        acc += vv.w * fast_tanh(f.w + d.w + ew);
    }
    for (int off = 32; off; off >>= 1) acc += __shfl_down(acc, off, 64);
    if (lane == 0) {
        if (word) wscores[row] = acc;
        else      sscores[row] = acc;
    }
}

// Per-batch fused middle: zero c_t, sent softmax, word softmax (in registers),
// ragged per-sentence renorm + coverage, sent_c_t. One block per b.
__global__ __launch_bounds__(256) void mid_kernel(
    float* __restrict__ attn,         // [B,T_K]  in: scores, out: attn
    const float* __restrict__ mask,   // [B,T_K]
    float* __restrict__ sattn,        // [B,64]   in: scores, out: attn
    const float* __restrict__ smask,  // [B,64]
    const float* __restrict__ senc,   // [B,64,N]
    float* __restrict__ sct,          // [B,N]
    const int* __restrict__ pos,      // [B,64] sorted sentence end positions
    const float* __restrict__ cov,    // [B,T_K]
    float* __restrict__ cov_out,      // [B,T_K]
    float* __restrict__ ct)           // [B,N] — zeroed here for ct_kernel's atomics
{
    int b = blockIdx.x, tid = threadIdx.x;
    int wid = tid >> 6, lane = tid & 63;
    __shared__ float sa[SENT_T];
    __shared__ float ssum[SENT_T];
    __shared__ int ends[SENT_T];
    __shared__ float redm[4], reds[4], red2[4];

    // zero c_t[b,:] for the downstream atomic reduction
    ct[b * NN + tid] = 0.f;
    ct[b * NN + tid + 256] = 0.f;

    // ---- sentence softmax (wave 0 only; 64 values) ----
    if (tid < SENT_T) {
        float s = sattn[b * SENT_T + tid];
        float m = s;
        for (int off = 32; off; off >>= 1) m = fmaxf(m, __shfl_xor(m, off, 64));
        float p = __expf(s - m);
        float sum = p;
        for (int off = 32; off; off >>= 1) sum += __shfl_xor(sum, off, 64);
        float a0 = p / sum * smask[b * SENT_T + tid];
        float s2 = a0;
        for (int off = 32; off; off >>= 1) s2 += __shfl_xor(s2, off, 64);
        float a = a0 / s2;
        sattn[b * SENT_T + tid] = a;
        sa[tid] = a;
        ends[tid] = pos[b * SENT_T + tid];
        ssum[tid] = 0.f;
    }

    // ---- word softmax over 2048, values live in registers (tokens tid*8..tid*8+7) ----
    const int base = b * T_K + tid * 8;
    float4 v0 = *reinterpret_cast<const float4*>(attn + base);
    float4 v1 = *reinterpret_cast<const float4*>(attn + base + 4);
    float vv[8] = {v0.x, v0.y, v0.z, v0.w, v1.x, v1.y, v1.z, v1.w};

    float m = vv[0];
#pragma unroll
    for (int i = 1; i < 8; ++i) m = fmaxf(m, vv[i]);
    for (int off = 32; off; off >>= 1) m = fmaxf(m, __shfl_xor(m, off, 64));
    if (lane == 0) redm[wid] = m;
    __syncthreads();                      // also publishes sa/ends/ssum
    m = fmaxf(fmaxf(redm[0], redm[1]), fmaxf(redm[2], redm[3]));

    float p[8], s = 0.f;
#pragma unroll
    for (int i = 0; i < 8; ++i) { p[i] = __expf(vv[i] - m); s += p[i]; }
    for (int off = 32; off; off >>= 1) s += __shfl_xor(s, off, 64);
    if (lane == 0) reds[wid] = s;
    __syncthreads();
    s = reds[0] + reds[1] + reds[2] + reds[3];

    float4 m0 = *reinterpret_cast<const float4*>(mask + base);
    float4 m1 = *reinterpret_cast<const float4*>(mask + base + 4);
    float mk[8] = {m0.x, m0.y, m0.z, m0.w, m1.x, m1.y, m1.z, m1.w};
    float a0[8], s2 = 0.f;
#pragma unroll
    for (int i = 0; i < 8; ++i) { a0[i] = p[i] / s * mk[i]; s2 += a0[i]; }
    for (int off = 32; off; off >>= 1) s2 += __shfl_xor(s2, off, 64);
    if (lane == 0) red2[wid] = s2;
    __syncthreads();
    s2 = red2[0] + red2[1] + red2[2] + red2[3];
    float r = 1.f / s2;

    float a[8];
    int seg[8];
#pragma unroll
    for (int i = 0; i < 8; ++i) {
        a[i] = a0[i] * r;
        int t = tid * 8 + i;
        int lo = 0, hi = SENT_T;
        while (lo < hi) { int mid = (lo + hi) >> 1; if (ends[mid] <= t) lo = mid + 1; else hi = mid; }
        seg[i] = lo;  // searchsorted(side='right')
        if (lo < SENT_T) atomicAdd(&ssum[lo], a[i]);
    }
    float4 o0 = {a[0], a[1], a[2], a[3]};
    float4 o1 = {a[4], a[5], a[6], a[7]};
    *reinterpret_cast<float4*>(attn + base) = o0;
    *reinterpret_cast<float4*>(attn + base + 4) = o1;
    __syncthreads();                      // ssum complete

    // ragged renorm + coverage
    float4 c0 = *reinterpret_cast<const float4*>(cov + base);
    float4 c1 = *reinterpret_cast<const float4*>(cov + base + 4);
    float cvv[8] = {c0.x, c0.y, c0.z, c0.w, c1.x, c1.y, c1.z, c1.w};
    float co[8];
#pragma unroll
    for (int i = 0; i < 8; ++i) {
        float sw = 0.f;
        if (seg[i] < SENT_T) sw = a[i] / ssum[seg[i]] * sa[seg[i]];
        co[i] = cvv[i] + sw;
    }
    float4 q0 = {co[0], co[1], co[2], co[3]};
    float4 q1 = {co[4], co[5], co[6], co[7]};
    *reinterpret_cast<float4*>(cov_out + base) = q0;
    *reinterpret_cast<float4*>(cov_out + base + 4) = q1;

    // sent_c_t: 256 threads sweep N, loop 64 sentences
    for (int n = tid; n < NN; n += 256) {
        float acc = 0.f;
#pragma unroll 8
        for (int t = 0; t < SENT_T; ++t)
            acc = fmaf(sa[t], senc[((size_t)b * SENT_T + t) * NN + n], acc);
        sct[b * NN + n] = acc;
    }
}

// c_t[b,:] += sum over a 64-token chunk; float4 loads (1KB per wave-instruction)
__global__ __launch_bounds__(256) void ct_kernel(
    const float* __restrict__ attn,  // [B,T_K] final attention
    const float* __restrict__ enc,   // [B,T_K,N]
    float* __restrict__ ct)          // [B,N] (zeroed by mid_kernel)
{
    int b = blockIdx.y, chunk = blockIdx.x, tid = threadIdx.x;
    __shared__ float a_sh[64];
    if (tid < 64) a_sh[tid] = attn[b * T_K + chunk * 64 + tid];
    __syncthreads();
    int p  = tid >> 7;    // row parity within the t-pair
    int c4 = tid & 127;   // float4 column index [0,128)
    const float4* base = reinterpret_cast<const float4*>(enc + ((size_t)b * T_K + (size_t)chunk * 64) * NN);
    float4 acc = {0.f, 0.f, 0.f, 0.f};
#pragma unroll 8
    for (int t = 0; t < 64; t += 2) {
        int rrow = t + p;
        float av = a_sh[rrow];
        float4 e = base[rrow * (NN / 4) + c4];
        acc.x = fmaf(av, e.x, acc.x);
        acc.y = fmaf(av, e.y, acc.y);
        acc.z = fmaf(av, e.z, acc.z);
        acc.w = fmaf(av, e.w, acc.w);
    }
    float* dst = ct + b * NN + c4 * 4;
    atomicAdd(dst + 0, acc.x);
    atomicAdd(dst + 1, acc.y);
    atomicAdd(dst + 2, acc.z);
    atomicAdd(dst + 3, acc.w);
}

extern "C" void kernel_launch(void* const* d_in, const int* in_sizes, int n_in,
                              void* d_out, int out_size, void* d_ws, size_t ws_size,
                              hipStream_t stream) {
    const float* s_t_hat          = (const float*)d_in[0];
    const int*   enc_sent_pos     = (const int*)d_in[1];
    const float* encoder_outputs  = (const float*)d_in[2];
    const float* encoder_feature  = (const float*)d_in[3];
    const float* enc_padding_mask = (const float*)d_in[4];
    const float* sent_s_t_hat     = (const float*)d_in[5];
    const float* sent_enc_outputs = (const float*)d_in[6];
    const float* sent_enc_feature = (const float*)d_in[7];
    const float* sent_enc_padding_mask = (const float*)d_in[8];
    const float* coverage         = (const float*)d_in[9];
    const float* W_dec            = (const float*)d_in[10];
    const float* b_dec            = (const float*)d_in[11];
    const float* v_w              = (const float*)d_in[12];
    const float* W_sent_dec       = (const float*)d_in[13];
    const float* b_sent_dec       = (const float*)d_in[14];
    const float* sent_v_w         = (const float*)d_in[15];
    const float* w_c              = (const float*)d_in[16];

    float* out         = (float*)d_out;
    float* c_t         = out;                       // [B,N]     8192
    float* attn_dist   = out + 8192;                // [B,T_K]   32768
    float* coverage_nw = out + 8192 + 32768;        // [B,T_K]   32768
    float* sent_c_t    = out + 8192 + 65536;        // [B,N]     8192
    float* sent_attn   = out + 16384 + 65536;       // [B,64]    1024

    float* ws   = (float*)d_ws;
    float* dec  = ws;            // [B,N]
    float* sdec = ws + BB * NN;  // [B,N]

    // 1) decoder projections (word + sent fused)
    dec_fused<<<2 * BB, 256, 0, stream>>>(s_t_hat, W_dec, b_dec,
                                          sent_s_t_hat, W_sent_dec, b_sent_dec,
                                          dec, sdec);

    // 2) all attention scores (word + sent fused); written into output attn slots
    scores_all<<<(WORD_ROWS + SENT_ROWS) / 4, 256, 0, stream>>>(
        encoder_feature, dec, v_w, w_c, coverage,
        sent_enc_feature, sdec, sent_v_w,
        attn_dist, sent_attn);

    // 3) softmaxes + ragged renorm + coverage + sent_c_t + zero(c_t)
    mid_kernel<<<BB, 256, 0, stream>>>(attn_dist, enc_padding_mask,
                                       sent_attn, sent_enc_padding_mask,
                                       sent_enc_outputs, sent_c_t,
                                       enc_sent_pos, coverage, coverage_nw, c_t);

    // 4) c_t reduction
    ct_kernel<<<dim3(T_K / 64, BB), 256, 0, stream>>>(attn_dist, encoder_outputs, c_t);
}

// Round 4
// 208.060 us; speedup vs baseline: 1.3342x; 1.1538x over previous
//
#include <hip/hip_runtime.h>

#define BB 16
#define T_K 2048
#define SENT_T 64
#define NN 512
#define WORD_ROWS (BB * T_K)     // 32768
#define SENT_ROWS (BB * SENT_T)  // 1024

// fast tanh: raw v_exp + raw v_rcp. Saturation exact (e->inf => 1, e->0 => -1).
__device__ __forceinline__ float fast_tanh(float x) {
    float e = __expf(2.f * x);
    return 1.f - 2.f * __builtin_amdgcn_rcpf(1.f + e);
}

// Decoder projections, both matrices. 256 blocks: [matrix(2)][b(16)][n-chunk(8)].
// Each block: 64 output rows, 4 k-quarter waves, LDS reduce.
__global__ __launch_bounds__(256) void dec_fused(
    const float* __restrict__ s_w, const float* __restrict__ W_w, const float* __restrict__ bias_w,
    const float* __restrict__ s_s, const float* __restrict__ W_s, const float* __restrict__ bias_s,
    float* __restrict__ dec, float* __restrict__ sdec)
{
    int blk = blockIdx.x;            // 0..255
    bool sent = blk >= 128;
    int sub = blk & 127;
    int b = sub >> 3;                // 0..15
    int n0 = (sub & 7) * 64;         // 0..448
    const float* s    = sent ? s_s    : s_w;
    const float* W    = sent ? W_s    : W_w;
    const float* bias = sent ? bias_s : bias_w;
    float* out        = sent ? sdec   : dec;

    __shared__ float sv[NN];
    __shared__ float part[4][64];
    for (int i = threadIdx.x; i < NN; i += 256) sv[i] = s[b * NN + i];
    __syncthreads();

    int kq  = threadIdx.x >> 6;      // wave id = k quarter
    int row = threadIdx.x & 63;
    const float4* Wr  = reinterpret_cast<const float4*>(W + (size_t)(n0 + row) * NN) + kq * 32;
    const float*  svq = sv + kq * 128;
    float acc = 0.f;
#pragma unroll
    for (int j = 0; j < 32; ++j) {
        float4 w4 = Wr[j];
        acc = fmaf(w4.x, svq[4 * j + 0], acc);
        acc = fmaf(w4.y, svq[4 * j + 1], acc);
        acc = fmaf(w4.z, svq[4 * j + 2], acc);
        acc = fmaf(w4.w, svq[4 * j + 3], acc);
    }
    part[kq][row] = acc;
    __syncthreads();
    if (threadIdx.x < 64) {
        float r = part[0][threadIdx.x] + part[1][threadIdx.x]
                + part[2][threadIdx.x] + part[3][threadIdx.x] + bias[n0 + threadIdx.x];
        out[b * NN + n0 + threadIdx.x] = r;
    }
}

// One wave per score row; word rows first, then sent rows. Branch is wave-uniform.
__global__ __launch_bounds__(256) void scores_all(
    const float* __restrict__ feat,  const float* __restrict__ dec,
    const float* __restrict__ v,     const float* __restrict__ wc,
    const float* __restrict__ cov,
    const float* __restrict__ sfeat, const float* __restrict__ sdec,
    const float* __restrict__ sv_,
    float* __restrict__ wscores, float* __restrict__ sscores)
{
    int gw = (blockIdx.x * 256 + threadIdx.x) >> 6;
    int lane = threadIdx.x & 63;
    bool word = gw < WORD_ROWS;
    int row = word ? gw : gw - WORD_ROWS;
    int b = word ? (row >> 11) : (row >> 6);

    const float4* f4 = reinterpret_cast<const float4*>((word ? feat : sfeat) + (size_t)row * NN);
    const float4* d4 = reinterpret_cast<const float4*>((word ? dec : sdec) + (size_t)b * NN);
    const float4* v4 = reinterpret_cast<const float4*>(word ? v : sv_);
    const float4* w4 = reinterpret_cast<const float4*>(wc);
    float c = word ? cov[row] : 0.f;

    float acc = 0.f;
#pragma unroll
    for (int i = 0; i < 2; ++i) {
        int idx = lane + 64 * i;  // float4 index within the 512-float row
        float4 f = f4[idx];
        float4 d = d4[idx];
        float4 vv = v4[idx];
        float ex = 0.f, ey = 0.f, ez = 0.f, ew = 0.f;
        if (word) {
            float4 w = w4[idx];
            ex = c * w.x; ey = c * w.y; ez = c * w.z; ew = c * w.w;
        }
        acc += vv.x * fast_tanh(f.x + d.x + ex);
        acc += vv.y * fast_tanh(f.y + d.y + ey);
        acc += vv.z * fast_tanh(f.z + d.z + ez);
        acc += vv.w * fast_tanh(f.w + d.w + ew);
    }
    for (int off = 32; off; off >>= 1) acc += __shfl_down(acc, off, 64);
    if (lane == 0) {
        if (word) wscores[row] = acc;
        else      sscores[row] = acc;
    }
}

// Per-batch fused middle: zero c_t, sent softmax, word softmax (registers),
// ragged per-sentence renorm + coverage. One block per b.
__global__ __launch_bounds__(256) void mid_kernel(
    float* __restrict__ attn,         // [B,T_K]  in: scores, out: attn
    const float* __restrict__ mask,   // [B,T_K]
    float* __restrict__ sattn,        // [B,64]   in: scores, out: attn
    const float* __restrict__ smask,  // [B,64]
    const int* __restrict__ pos,      // [B,64] sorted sentence end positions
    const float* __restrict__ cov,    // [B,T_K]
    float* __restrict__ cov_out,      // [B,T_K]
    float* __restrict__ ct)           // [B,N] — zeroed here for ct_kernel's atomics
{
    int b = blockIdx.x, tid = threadIdx.x;
    int wid = tid >> 6, lane = tid & 63;
    __shared__ float sa[SENT_T];
    __shared__ float ssum[SENT_T];
    __shared__ int ends[SENT_T];
    __shared__ float redm[4], reds[4], red2[4];

    // zero c_t[b,:] for the downstream atomic reduction
    ct[b * NN + tid] = 0.f;
    ct[b * NN + tid + 256] = 0.f;

    // ---- sentence softmax (wave 0 only; 64 values) ----
    if (tid < SENT_T) {
        float s = sattn[b * SENT_T + tid];
        float m = s;
        for (int off = 32; off; off >>= 1) m = fmaxf(m, __shfl_xor(m, off, 64));
        float p = __expf(s - m);
        float sum = p;
        for (int off = 32; off; off >>= 1) sum += __shfl_xor(sum, off, 64);
        float a0 = p / sum * smask[b * SENT_T + tid];
        float s2 = a0;
        for (int off = 32; off; off >>= 1) s2 += __shfl_xor(s2, off, 64);
        float a = a0 / s2;
        sattn[b * SENT_T + tid] = a;
        sa[tid] = a;
        ends[tid] = pos[b * SENT_T + tid];
        ssum[tid] = 0.f;
    }

    // ---- word softmax over 2048, values in registers (tokens tid*8..tid*8+7) ----
    const int base = b * T_K + tid * 8;
    float4 v0 = *reinterpret_cast<const float4*>(attn + base);
    float4 v1 = *reinterpret_cast<const float4*>(attn + base + 4);
    float vv[8] = {v0.x, v0.y, v0.z, v0.w, v1.x, v1.y, v1.z, v1.w};

    float m = vv[0];
#pragma unroll
    for (int i = 1; i < 8; ++i) m = fmaxf(m, vv[i]);
    for (int off = 32; off; off >>= 1) m = fmaxf(m, __shfl_xor(m, off, 64));
    if (lane == 0) redm[wid] = m;
    __syncthreads();                      // also publishes sa/ends/ssum
    m = fmaxf(fmaxf(redm[0], redm[1]), fmaxf(redm[2], redm[3]));

    float p[8], s = 0.f;
#pragma unroll
    for (int i = 0; i < 8; ++i) { p[i] = __expf(vv[i] - m); s += p[i]; }
    for (int off = 32; off; off >>= 1) s += __shfl_xor(s, off, 64);
    if (lane == 0) reds[wid] = s;
    __syncthreads();
    s = reds[0] + reds[1] + reds[2] + reds[3];

    float4 m0 = *reinterpret_cast<const float4*>(mask + base);
    float4 m1 = *reinterpret_cast<const float4*>(mask + base + 4);
    float mk[8] = {m0.x, m0.y, m0.z, m0.w, m1.x, m1.y, m1.z, m1.w};
    float a0[8], s2 = 0.f;
#pragma unroll
    for (int i = 0; i < 8; ++i) { a0[i] = p[i] / s * mk[i]; s2 += a0[i]; }
    for (int off = 32; off; off >>= 1) s2 += __shfl_xor(s2, off, 64);
    if (lane == 0) red2[wid] = s2;
    __syncthreads();
    s2 = red2[0] + red2[1] + red2[2] + red2[3];
    float r = 1.f / s2;

    float a[8];
    int seg[8];
#pragma unroll
    for (int i = 0; i < 8; ++i) {
        a[i] = a0[i] * r;
        int t = tid * 8 + i;
        int lo = 0, hi = SENT_T;
        while (lo < hi) { int mid = (lo + hi) >> 1; if (ends[mid] <= t) lo = mid + 1; else hi = mid; }
        seg[i] = lo;  // searchsorted(side='right')
        if (lo < SENT_T) atomicAdd(&ssum[lo], a[i]);
    }
    float4 o0 = {a[0], a[1], a[2], a[3]};
    float4 o1 = {a[4], a[5], a[6], a[7]};
    *reinterpret_cast<float4*>(attn + base) = o0;
    *reinterpret_cast<float4*>(attn + base + 4) = o1;
    __syncthreads();                      // ssum complete

    // ragged renorm + coverage
    float4 c0 = *reinterpret_cast<const float4*>(cov + base);
    float4 c1 = *reinterpret_cast<const float4*>(cov + base + 4);
    float cvv[8] = {c0.x, c0.y, c0.z, c0.w, c1.x, c1.y, c1.z, c1.w};
    float co[8];
#pragma unroll
    for (int i = 0; i < 8; ++i) {
        float sw = 0.f;
        if (seg[i] < SENT_T) sw = a[i] / ssum[seg[i]] * sa[seg[i]];
        co[i] = cvv[i] + sw;
    }
    float4 q0 = {co[0], co[1], co[2], co[3]};
    float4 q1 = {co[4], co[5], co[6], co[7]};
    *reinterpret_cast<float4*>(cov_out + base) = q0;
    *reinterpret_cast<float4*>(cov_out + base + 4) = q1;
}

// grid (33, B): x<32 -> word c_t partial over a 64-token chunk (float4 loads,
// atomic finish); x==32 -> sent_c_t for batch b (senc is L2/L3-resident, 2MB).
__global__ __launch_bounds__(256) void ct_kernel(
    const float* __restrict__ attn,   // [B,T_K] final word attention
    const float* __restrict__ enc,    // [B,T_K,N]
    const float* __restrict__ sattn,  // [B,64] final sent attention
    const float* __restrict__ senc,   // [B,64,N]
    float* __restrict__ ct,           // [B,N] (zeroed by mid_kernel)
    float* __restrict__ sct)          // [B,N]
{
    int b = blockIdx.y, tid = threadIdx.x;
    if (blockIdx.x == 32) {
        __shared__ float sa_sh[SENT_T];
        if (tid < SENT_T) sa_sh[tid] = sattn[b * SENT_T + tid];
        __syncthreads();
        const float* basep = senc + (size_t)b * SENT_T * NN;
        float acc0 = 0.f, acc1 = 0.f;
#pragma unroll 8
        for (int t = 0; t < SENT_T; ++t) {
            float av = sa_sh[t];
            acc0 = fmaf(av, basep[t * NN + tid], acc0);
            acc1 = fmaf(av, basep[t * NN + tid + 256], acc1);
        }
        sct[b * NN + tid] = acc0;
        sct[b * NN + tid + 256] = acc1;
        return;
    }
    int chunk = blockIdx.x;
    __shared__ float a_sh[64];
    if (tid < 64) a_sh[tid] = attn[b * T_K + chunk * 64 + tid];
    __syncthreads();
    int p  = tid >> 7;    // row parity within the t-pair
    int c4 = tid & 127;   // float4 column index [0,128)
    const float4* base = reinterpret_cast<const float4*>(enc + ((size_t)b * T_K + (size_t)chunk * 64) * NN);
    float4 acc = {0.f, 0.f, 0.f, 0.f};
#pragma unroll 8
    for (int t = 0; t < 64; t += 2) {
        int rrow = t + p;
        float av = a_sh[rrow];
        float4 e = base[rrow * (NN / 4) + c4];
        acc.x = fmaf(av, e.x, acc.x);
        acc.y = fmaf(av, e.y, acc.y);
        acc.z = fmaf(av, e.z, acc.z);
        acc.w = fmaf(av, e.w, acc.w);
    }
    float* dst = ct + b * NN + c4 * 4;
    atomicAdd(dst + 0, acc.x);
    atomicAdd(dst + 1, acc.y);
    atomicAdd(dst + 2, acc.z);
    atomicAdd(dst + 3, acc.w);
}

extern "C" void kernel_launch(void* const* d_in, const int* in_sizes, int n_in,
                              void* d_out, int out_size, void* d_ws, size_t ws_size,
                              hipStream_t stream) {
    const float* s_t_hat          = (const float*)d_in[0];
    const int*   enc_sent_pos     = (const int*)d_in[1];
    const float* encoder_outputs  = (const float*)d_in[2];
    const float* encoder_feature  = (const float*)d_in[3];
    const float* enc_padding_mask = (const float*)d_in[4];
    const float* sent_s_t_hat     = (const float*)d_in[5];
    const float* sent_enc_outputs = (const float*)d_in[6];
    const float* sent_enc_feature = (const float*)d_in[7];
    const float* sent_enc_padding_mask = (const float*)d_in[8];
    const float* coverage         = (const float*)d_in[9];
    const float* W_dec            = (const float*)d_in[10];
    const float* b_dec            = (const float*)d_in[11];
    const float* v_w              = (const float*)d_in[12];
    const float* W_sent_dec       = (const float*)d_in[13];
    const float* b_sent_dec       = (const float*)d_in[14];
    const float* sent_v_w         = (const float*)d_in[15];
    const float* w_c              = (const float*)d_in[16];

    float* out         = (float*)d_out;
    float* c_t         = out;                       // [B,N]     8192
    float* attn_dist   = out + 8192;                // [B,T_K]   32768
    float* coverage_nw = out + 8192 + 32768;        // [B,T_K]   32768
    float* sent_c_t    = out + 8192 + 65536;        // [B,N]     8192
    float* sent_attn   = out + 16384 + 65536;       // [B,64]    1024

    float* ws   = (float*)d_ws;
    float* dec  = ws;            // [B,N]
    float* sdec = ws + BB * NN;  // [B,N]

    // 1) decoder projections (word + sent fused, 256 blocks)
    dec_fused<<<256, 256, 0, stream>>>(s_t_hat, W_dec, b_dec,
                                       sent_s_t_hat, W_sent_dec, b_sent_dec,
                                       dec, sdec);

    // 2) all attention scores (word + sent fused); written into output attn slots
    scores_all<<<(WORD_ROWS + SENT_ROWS) / 4, 256, 0, stream>>>(
        encoder_feature, dec, v_w, w_c, coverage,
        sent_enc_feature, sdec, sent_v_w,
        attn_dist, sent_attn);

    // 3) softmaxes + ragged renorm + coverage + zero(c_t)
    mid_kernel<<<BB, 256, 0, stream>>>(attn_dist, enc_padding_mask,
                                       sent_attn, sent_enc_padding_mask,
                                       enc_sent_pos, coverage, coverage_nw, c_t);

    // 4) c_t + sent_c_t reductions
    ct_kernel<<<dim3(33, BB), 256, 0, stream>>>(attn_dist, encoder_outputs,
                                                sent_attn, sent_enc_outputs,
                                                c_t, sent_c_t);
}

// Round 6
// 204.692 us; speedup vs baseline: 1.3562x; 1.0165x over previous
//
#include <hip/hip_runtime.h>

#define BB 16
#define T_K 2048
#define SENT_T 64
#define NN 512
#define WORD_ROWS (BB * T_K)     // 32768
#define SENT_ROWS (BB * SENT_T)  // 1024

typedef float nfloat4 __attribute__((ext_vector_type(4)));

// fast tanh: raw v_exp + raw v_rcp. Saturation exact (e->inf => 1, e->0 => -1).
__device__ __forceinline__ float fast_tanh(float x) {
    float e = __expf(2.f * x);
    return 1.f - 2.f * __builtin_amdgcn_rcpf(1.f + e);
}

// nontemporal float4 load (read-once streams; sets nt, skips cache retention).
// __builtin_nontemporal_load needs a native vector type, not HIP_vector_type.
__device__ __forceinline__ float4 ldnt(const float4* p) {
    nfloat4 r = __builtin_nontemporal_load(reinterpret_cast<const nfloat4*>(p));
    return make_float4(r.x, r.y, r.z, r.w);
}

// Decoder projections, both matrices. 256 blocks: [matrix(2)][b(16)][n-chunk(8)].
// Each block: 64 output rows, 4 k-quarter waves, LDS reduce.
__global__ __launch_bounds__(256) void dec_fused(
    const float* __restrict__ s_w, const float* __restrict__ W_w, const float* __restrict__ bias_w,
    const float* __restrict__ s_s, const float* __restrict__ W_s, const float* __restrict__ bias_s,
    float* __restrict__ dec, float* __restrict__ sdec)
{
    int blk = blockIdx.x;            // 0..255
    bool sent = blk >= 128;
    int sub = blk & 127;
    int b = sub >> 3;                // 0..15
    int n0 = (sub & 7) * 64;         // 0..448
    const float* s    = sent ? s_s    : s_w;
    const float* W    = sent ? W_s    : W_w;
    const float* bias = sent ? bias_s : bias_w;
    float* out        = sent ? sdec   : dec;

    __shared__ float sv[NN];
    __shared__ float part[4][64];
    for (int i = threadIdx.x; i < NN; i += 256) sv[i] = s[b * NN + i];
    __syncthreads();

    int kq  = threadIdx.x >> 6;      // wave id = k quarter
    int row = threadIdx.x & 63;
    const float4* Wr  = reinterpret_cast<const float4*>(W + (size_t)(n0 + row) * NN) + kq * 32;
    const float*  svq = sv + kq * 128;
    float acc = 0.f;
#pragma unroll
    for (int j = 0; j < 32; ++j) {
        float4 w4 = Wr[j];
        acc = fmaf(w4.x, svq[4 * j + 0], acc);
        acc = fmaf(w4.y, svq[4 * j + 1], acc);
        acc = fmaf(w4.z, svq[4 * j + 2], acc);
        acc = fmaf(w4.w, svq[4 * j + 3], acc);
    }
    part[kq][row] = acc;
    __syncthreads();
    if (threadIdx.x < 64) {
        float r = part[0][threadIdx.x] + part[1][threadIdx.x]
                + part[2][threadIdx.x] + part[3][threadIdx.x] + bias[n0 + threadIdx.x];
        out[b * NN + n0 + threadIdx.x] = r;
    }
}

// One wave per score row; word rows first, then sent rows. Branch is wave-uniform.
// All loads hoisted before the transcendental chain for max MLP.
__global__ __launch_bounds__(256) void scores_all(
    const float* __restrict__ feat,  const float* __restrict__ dec,
    const float* __restrict__ v,     const float* __restrict__ wc,
    const float* __restrict__ cov,
    const float* __restrict__ sfeat, const float* __restrict__ sdec,
    const float* __restrict__ sv_,
    float* __restrict__ wscores, float* __restrict__ sscores)
{
    int gw = (blockIdx.x * 256 + threadIdx.x) >> 6;
    int lane = threadIdx.x & 63;
    bool word = gw < WORD_ROWS;
    int row = word ? gw : gw - WORD_ROWS;
    int b = word ? (row >> 11) : (row >> 6);

    const float4* f4 = reinterpret_cast<const float4*>((word ? feat : sfeat) + (size_t)row * NN);
    const float4* d4 = reinterpret_cast<const float4*>((word ? dec : sdec) + (size_t)b * NN);
    const float4* v4 = reinterpret_cast<const float4*>(word ? v : sv_);
    const float4* w4 = reinterpret_cast<const float4*>(wc);
    float c = word ? cov[row] : 0.f;

    // hoist all global loads (feat is the 64MB read-once stream -> nt)
    float4 f0 = ldnt(f4 + lane);
    float4 f1 = ldnt(f4 + lane + 64);
    float4 d0 = d4[lane];
    float4 d1 = d4[lane + 64];
    float4 q0 = v4[lane];
    float4 q1 = v4[lane + 64];
    float4 w0 = w4[lane];
    float4 w1 = w4[lane + 64];
    if (!word) { w0 = {0.f, 0.f, 0.f, 0.f}; w1 = w0; }

    float acc = 0.f;
    acc += q0.x * fast_tanh(f0.x + d0.x + c * w0.x);
    acc += q0.y * fast_tanh(f0.y + d0.y + c * w0.y);
    acc += q0.z * fast_tanh(f0.z + d0.z + c * w0.z);
    acc += q0.w * fast_tanh(f0.w + d0.w + c * w0.w);
    acc += q1.x * fast_tanh(f1.x + d1.x + c * w1.x);
    acc += q1.y * fast_tanh(f1.y + d1.y + c * w1.y);
    acc += q1.z * fast_tanh(f1.z + d1.z + c * w1.z);
    acc += q1.w * fast_tanh(f1.w + d1.w + c * w1.w);

    for (int off = 32; off; off >>= 1) acc += __shfl_down(acc, off, 64);
    if (lane == 0) {
        if (word) wscores[row] = acc;
        else      sscores[row] = acc;
    }
}

// Per-batch fused middle: zero c_t, sent softmax, word softmax (registers),
// ragged per-sentence renorm + coverage. One block per b.
__global__ __launch_bounds__(256) void mid_kernel(
    float* __restrict__ attn,         // [B,T_K]  in: scores, out: attn
    const float* __restrict__ mask,   // [B,T_K]
    float* __restrict__ sattn,        // [B,64]   in: scores, out: attn
    const float* __restrict__ smask,  // [B,64]
    const int* __restrict__ pos,      // [B,64] sorted sentence end positions
    const float* __restrict__ cov,    // [B,T_K]
    float* __restrict__ cov_out,      // [B,T_K]
    float* __restrict__ ct)           // [B,N] — zeroed here for ct_kernel's atomics
{
    int b = blockIdx.x, tid = threadIdx.x;
    int wid = tid >> 6, lane = tid & 63;
    __shared__ float sa[SENT_T];
    __shared__ float ssum[SENT_T];
    __shared__ int ends[SENT_T];
    __shared__ float redm[4], reds[4], red2[4];

    // zero c_t[b,:] (float4: first 128 threads cover 512 floats)
    if (tid < 128) {
        float4 z = {0.f, 0.f, 0.f, 0.f};
        reinterpret_cast<float4*>(ct + b * NN)[tid] = z;
    }

    // ---- sentence softmax (wave 0 only; 64 values) ----
    if (tid < SENT_T) {
        float s = sattn[b * SENT_T + tid];
        float m = s;
        for (int off = 32; off; off >>= 1) m = fmaxf(m, __shfl_xor(m, off, 64));
        float p = __expf(s - m);
        float sum = p;
        for (int off = 32; off; off >>= 1) sum += __shfl_xor(sum, off, 64);
        float a0 = p / sum * smask[b * SENT_T + tid];
        float s2 = a0;
        for (int off = 32; off; off >>= 1) s2 += __shfl_xor(s2, off, 64);
        float a = a0 / s2;
        sattn[b * SENT_T + tid] = a;
        sa[tid] = a;
        ends[tid] = pos[b * SENT_T + tid];
        ssum[tid] = 0.f;
    }

    // ---- word softmax over 2048, values in registers (tokens tid*8..tid*8+7) ----
    const int base = b * T_K + tid * 8;
    float4 v0 = *reinterpret_cast<const float4*>(attn + base);
    float4 v1 = *reinterpret_cast<const float4*>(attn + base + 4);
    float vv[8] = {v0.x, v0.y, v0.z, v0.w, v1.x, v1.y, v1.z, v1.w};

    float m = vv[0];
#pragma unroll
    for (int i = 1; i < 8; ++i) m = fmaxf(m, vv[i]);
    for (int off = 32; off; off >>= 1) m = fmaxf(m, __shfl_xor(m, off, 64));
    if (lane == 0) redm[wid] = m;
    __syncthreads();                      // also publishes sa/ends/ssum
    m = fmaxf(fmaxf(redm[0], redm[1]), fmaxf(redm[2], redm[3]));

    float p[8], s = 0.f;
#pragma unroll
    for (int i = 0; i < 8; ++i) { p[i] = __expf(vv[i] - m); s += p[i]; }
    for (int off = 32; off; off >>= 1) s += __shfl_xor(s, off, 64);
    if (lane == 0) reds[wid] = s;
    __syncthreads();
    s = reds[0] + reds[1] + reds[2] + reds[3];

    float4 m0 = *reinterpret_cast<const float4*>(mask + base);
    float4 m1 = *reinterpret_cast<const float4*>(mask + base + 4);
    float mk[8] = {m0.x, m0.y, m0.z, m0.w, m1.x, m1.y, m1.z, m1.w};
    float a0[8], s2 = 0.f;
#pragma unroll
    for (int i = 0; i < 8; ++i) { a0[i] = p[i] / s * mk[i]; s2 += a0[i]; }
    for (int off = 32; off; off >>= 1) s2 += __shfl_xor(s2, off, 64);
    if (lane == 0) red2[wid] = s2;
    __syncthreads();
    s2 = red2[0] + red2[1] + red2[2] + red2[3];
    float r = 1.f / s2;

    float a[8];
    int seg[8];
#pragma unroll
    for (int i = 0; i < 8; ++i) {
        a[i] = a0[i] * r;
        int t = tid * 8 + i;
        int lo = 0, hi = SENT_T;
        while (lo < hi) { int mid = (lo + hi) >> 1; if (ends[mid] <= t) lo = mid + 1; else hi = mid; }
        seg[i] = lo;  // searchsorted(side='right')
        if (lo < SENT_T) atomicAdd(&ssum[lo], a[i]);
    }
    float4 o0 = {a[0], a[1], a[2], a[3]};
    float4 o1 = {a[4], a[5], a[6], a[7]};
    *reinterpret_cast<float4*>(attn + base) = o0;
    *reinterpret_cast<float4*>(attn + base + 4) = o1;
    __syncthreads();                      // ssum complete

    // ragged renorm + coverage
    float4 c0 = *reinterpret_cast<const float4*>(cov + base);
    float4 c1 = *reinterpret_cast<const float4*>(cov + base + 4);
    float cvv[8] = {c0.x, c0.y, c0.z, c0.w, c1.x, c1.y, c1.z, c1.w};
    float co[8];
#pragma unroll
    for (int i = 0; i < 8; ++i) {
        float sw = 0.f;
        if (seg[i] < SENT_T) sw = a[i] / ssum[seg[i]] * sa[seg[i]];
        co[i] = cvv[i] + sw;
    }
    float4 qq0 = {co[0], co[1], co[2], co[3]};
    float4 qq1 = {co[4], co[5], co[6], co[7]};
    *reinterpret_cast<float4*>(cov_out + base) = qq0;
    *reinterpret_cast<float4*>(cov_out + base + 4) = qq1;
}

// grid (33, B): x<32 -> word c_t partial over a 64-token chunk (nt float4 loads,
// atomic finish); x==32 -> sent_c_t for batch b.
__global__ __launch_bounds__(256) void ct_kernel(
    const float* __restrict__ attn,   // [B,T_K] final word attention
    const float* __restrict__ enc,    // [B,T_K,N]
    const float* __restrict__ sattn,  // [B,64] final sent attention
    const float* __restrict__ senc,   // [B,64,N]
    float* __restrict__ ct,           // [B,N] (zeroed by mid_kernel)
    float* __restrict__ sct)          // [B,N]
{
    int b = blockIdx.y, tid = threadIdx.x;
    if (blockIdx.x == 32) {
        __shared__ float sa_sh[SENT_T];
        if (tid < SENT_T) sa_sh[tid] = sattn[b * SENT_T + tid];
        __syncthreads();
        const float* basep = senc + (size_t)b * SENT_T * NN;
        float acc0 = 0.f, acc1 = 0.f;
#pragma unroll 8
        for (int t = 0; t < SENT_T; ++t) {
            float av = sa_sh[t];
            acc0 = fmaf(av, basep[t * NN + tid], acc0);
            acc1 = fmaf(av, basep[t * NN + tid + 256], acc1);
        }
        sct[b * NN + tid] = acc0;
        sct[b * NN + tid + 256] = acc1;
        return;
    }
    int chunk = blockIdx.x;
    __shared__ float a_sh[64];
    if (tid < 64) a_sh[tid] = attn[b * T_K + chunk * 64 + tid];
    __syncthreads();
    int p  = tid >> 7;    // row parity within the t-pair
    int c4 = tid & 127;   // float4 column index [0,128)
    const float4* base = reinterpret_cast<const float4*>(enc + ((size_t)b * T_K + (size_t)chunk * 64) * NN);
    float4 acc = {0.f, 0.f, 0.f, 0.f};
#pragma unroll 8
    for (int t = 0; t < 64; t += 2) {
        int rrow = t + p;
        float av = a_sh[rrow];
        float4 e = ldnt(base + rrow * (NN / 4) + c4);   // enc is the 64MB read-once stream
        acc.x = fmaf(av, e.x, acc.x);
        acc.y = fmaf(av, e.y, acc.y);
        acc.z = fmaf(av, e.z, acc.z);
        acc.w = fmaf(av, e.w, acc.w);
    }
    float* dst = ct + b * NN + c4 * 4;
    atomicAdd(dst + 0, acc.x);
    atomicAdd(dst + 1, acc.y);
    atomicAdd(dst + 2, acc.z);
    atomicAdd(dst + 3, acc.w);
}

extern "C" void kernel_launch(void* const* d_in, const int* in_sizes, int n_in,
                              void* d_out, int out_size, void* d_ws, size_t ws_size,
                              hipStream_t stream) {
    const float* s_t_hat          = (const float*)d_in[0];
    const int*   enc_sent_pos     = (const int*)d_in[1];
    const float* encoder_outputs  = (const float*)d_in[2];
    const float* encoder_feature  = (const float*)d_in[3];
    const float* enc_padding_mask = (const float*)d_in[4];
    const float* sent_s_t_hat     = (const float*)d_in[5];
    const float* sent_enc_outputs = (const float*)d_in[6];
    const float* sent_enc_feature = (const float*)d_in[7];
    const float* sent_enc_padding_mask = (const float*)d_in[8];
    const float* coverage         = (const float*)d_in[9];
    const float* W_dec            = (const float*)d_in[10];
    const float* b_dec            = (const float*)d_in[11];
    const float* v_w              = (const float*)d_in[12];
    const float* W_sent_dec       = (const float*)d_in[13];
    const float* b_sent_dec       = (const float*)d_in[14];
    const float* sent_v_w         = (const float*)d_in[15];
    const float* w_c              = (const float*)d_in[16];

    float* out         = (float*)d_out;
    float* c_t         = out;                       // [B,N]     8192
    float* attn_dist   = out + 8192;                // [B,T_K]   32768
    float* coverage_nw = out + 8192 + 32768;        // [B,T_K]   32768
    float* sent_c_t    = out + 8192 + 65536;        // [B,N]     8192
    float* sent_attn   = out + 16384 + 65536;       // [B,64]    1024

    float* ws   = (float*)d_ws;
    float* dec  = ws;            // [B,N]
    float* sdec = ws + BB * NN;  // [B,N]

    // 1) decoder projections (word + sent fused, 256 blocks)
    dec_fused<<<256, 256, 0, stream>>>(s_t_hat, W_dec, b_dec,
                                       sent_s_t_hat, W_sent_dec, b_sent_dec,
                                       dec, sdec);

    // 2) all attention scores (word + sent fused); written into output attn slots
    scores_all<<<(WORD_ROWS + SENT_ROWS) / 4, 256, 0, stream>>>(
        encoder_feature, dec, v_w, w_c, coverage,
        sent_enc_feature, sdec, sent_v_w,
        attn_dist, sent_attn);

    // 3) softmaxes + ragged renorm + coverage + zero(c_t)
    mid_kernel<<<BB, 256, 0, stream>>>(attn_dist, enc_padding_mask,
                                       sent_attn, sent_enc_padding_mask,
                                       enc_sent_pos, coverage, coverage_nw, c_t);

    // 4) c_t + sent_c_t reductions
    ct_kernel<<<dim3(33, BB), 256, 0, stream>>>(attn_dist, encoder_outputs,
                                                sent_attn, sent_enc_outputs,
                                                c_t, sent_c_t);
}